// Round 1
// baseline (1630.958 us; speedup 1.0000x reference)
//
#include <hip/hip_runtime.h>

#define LNUM 4
#define BB 16
#define SS 16
#define KVC 2048
#define HH 6
#define DD 128
#define HIDN 768
#define FFN 2048
#define NCH 17          // 16 cache chunks of 128 keys + 1 "new keys" chunk
#define CK 128
#define ATT_SCALE 0.08838834764831845f

typedef short s16x8 __attribute__((ext_vector_type(8)));
typedef float f32x4 __attribute__((ext_vector_type(4)));

__device__ __forceinline__ short f2bf(float f) {
    union { float f; unsigned u; } x; x.f = f;
    unsigned r = (x.u + 0x7fffu + ((x.u >> 16) & 1u)) >> 16;
    return (short)r;
}

// ---------------- RMSNorm: one wave per token row (768 elems = 64 lanes * 12) ----------
__global__ __launch_bounds__(64) void rmsnorm_k(const float* __restrict__ x,
                                                const float* __restrict__ w,
                                                float* __restrict__ y) {
    int row = blockIdx.x, lane = threadIdx.x;
    const float* xp = x + (size_t)row * HIDN + lane * 12;
    float4 a = *(const float4*)xp;
    float4 b = *(const float4*)(xp + 4);
    float4 c = *(const float4*)(xp + 8);
    float s = a.x*a.x + a.y*a.y + a.z*a.z + a.w*a.w
            + b.x*b.x + b.y*b.y + b.z*b.z + b.w*b.w
            + c.x*c.x + c.y*c.y + c.z*c.z + c.w*c.w;
    for (int m = 1; m < 64; m <<= 1) s += __shfl_xor(s, m);
    float rq = rsqrtf(s * (1.f / 768.f) + 1e-6f);
    const float* wp = w + lane * 12;
    float4 wa = *(const float4*)wp;
    float4 wb = *(const float4*)(wp + 4);
    float4 wc = *(const float4*)(wp + 8);
    float* yp = y + (size_t)row * HIDN + lane * 12;
    float4 o;
    o.x = a.x*rq*wa.x; o.y = a.y*rq*wa.y; o.z = a.z*rq*wa.z; o.w = a.w*rq*wa.w;
    *(float4*)yp = o;
    o.x = b.x*rq*wb.x; o.y = b.y*rq*wb.y; o.z = b.z*rq*wb.z; o.w = b.w*rq*wb.w;
    *(float4*)(yp + 4) = o;
    o.x = c.x*rq*wc.x; o.y = c.y*rq*wc.y; o.z = c.z*rq*wc.z; o.w = c.w*rq*wc.w;
    *(float4*)(yp + 8) = o;
}

// ---------------- GEMM: C[256 x N] = A[256 x K] @ W[K x N] (+bias | += resid) ----------
// One wave per WG. MT m-tiles of 16 rows each. blockIdx.z selects W/bias/C (fused QKV / GU).
// MFMA 16x16x32 bf16, fp32 accum. A-frag: row = lane&15, k = (lane>>4)*8+j.
// B-frag: col = lane&15, k = (lane>>4)*8+j. D: col = lane&15, row = (lane>>4)*4+reg.
template<int MT, int EPI>
__global__ __launch_bounds__(64) void gemm_k(
    const float* __restrict__ A,
    const float* __restrict__ W0, const float* __restrict__ W1, const float* __restrict__ W2,
    const float* __restrict__ b0, const float* __restrict__ b1, const float* __restrict__ b2,
    float* __restrict__ C0, float* __restrict__ C1, float* __restrict__ C2,
    int K, int N) {
    int z = blockIdx.z;
    const float* W    = (z == 0) ? W0 : (z == 1) ? W1 : W2;
    const float* bias = (z == 0) ? b0 : (z == 1) ? b1 : b2;
    float*       C    = (z == 0) ? C0 : (z == 1) ? C1 : C2;
    int lane = threadIdx.x, r = lane & 15, g = lane >> 4;
    int n0 = blockIdx.x * 16;
    int m0 = blockIdx.y * MT;
    f32x4 acc[MT];
#pragma unroll
    for (int mt = 0; mt < MT; ++mt) acc[mt] = (f32x4){0.f, 0.f, 0.f, 0.f};
    for (int k0 = 0; k0 < K; k0 += 32) {
        s16x8 bw;
        const float* wp = W + (size_t)(k0 + g * 8) * N + n0 + r;
#pragma unroll
        for (int j = 0; j < 8; ++j) bw[j] = f2bf(wp[(size_t)j * N]);
#pragma unroll
        for (int mt = 0; mt < MT; ++mt) {
            const float* ap = A + (size_t)((m0 + mt) * 16 + r) * K + k0 + g * 8;
            float4 a0 = *(const float4*)ap;
            float4 a1 = *(const float4*)(ap + 4);
            s16x8 aw;
            aw[0]=f2bf(a0.x); aw[1]=f2bf(a0.y); aw[2]=f2bf(a0.z); aw[3]=f2bf(a0.w);
            aw[4]=f2bf(a1.x); aw[5]=f2bf(a1.y); aw[6]=f2bf(a1.z); aw[7]=f2bf(a1.w);
            acc[mt] = __builtin_amdgcn_mfma_f32_16x16x32_bf16(aw, bw, acc[mt], 0, 0, 0);
        }
    }
#pragma unroll
    for (int mt = 0; mt < MT; ++mt) {
#pragma unroll
        for (int v = 0; v < 4; ++v) {
            int row = (m0 + mt) * 16 + g * 4 + v;
            int col = n0 + r;
            size_t idx = (size_t)row * N + col;
            float val = acc[mt][v];
            if (EPI == 0) {
                if (bias) val += bias[col];
                C[idx] = val;
            } else {
                C[idx] += val;   // residual accumulate; each (row,col) owned by one WG
            }
        }
    }
}

// ---------------- RoPE + rearrange (b,s,h*d) -> (b,h,s,d); positions = KV + s ----------
__global__ __launch_bounds__(64) void rope_k(const float* __restrict__ qb,
                                             const float* __restrict__ kb,
                                             const float* __restrict__ vb,
                                             float* __restrict__ qr,
                                             float* __restrict__ kr,
                                             float* __restrict__ vr) {
    int bs = blockIdx.x;          // b*16 + s
    int h  = blockIdx.y;
    int d  = threadIdx.x;         // 0..63 (pair d, d+64)
    int b = bs >> 4, s = bs & 15;
    size_t ibase = (size_t)bs * HIDN + h * DD;
    size_t obase = (size_t)((b * HH + h) * SS + s) * DD;
    float pos = (float)(KVC + s);
    float ts  = powf(10000.f, (float)d * (1.f / 64.f));
    float rad = pos / ts;
    float sn = sinf(rad), cs = cosf(rad);
    float q1 = qb[ibase + d], q2 = qb[ibase + 64 + d];
    qr[obase + d]      = q1 * cs - q2 * sn;
    qr[obase + 64 + d] = q2 * cs + q1 * sn;
    float k1 = kb[ibase + d], k2 = kb[ibase + 64 + d];
    kr[obase + d]      = k1 * cs - k2 * sn;
    kr[obase + 64 + d] = k2 * cs + k1 * sn;
    vr[obase + d]      = vb[ibase + d];
    vr[obase + 64 + d] = vb[ibase + 64 + d];
}

// ---------------- Flash attention partials: 1 wave per (b*h, key-chunk) --------------
// Chunk 0..15: 128 cache keys. Chunk 16: the 16 new keys (causal-masked).
// Q: 16 x 128 in bf16 frags. Scores/softmax state fp32. P bounced via LDS to A-layout.
__global__ __launch_bounds__(64) void attn_part_k(
    const float* __restrict__ qr, const float* __restrict__ kr, const float* __restrict__ vr,
    const float* __restrict__ kc, const float* __restrict__ vc,
    float* __restrict__ part_o, float* __restrict__ part_ml) {
    int bh = blockIdx.x;          // 0..95
    int ch = blockIdx.y;          // 0..16
    int lane = threadIdx.x, r = lane & 15, g = lane >> 4;
    bool isnew = (ch == NCH - 1);
    const float* kbase = isnew ? (kr + (size_t)bh * SS * DD)
                               : (kc + (size_t)(bh * KVC + ch * CK) * DD);
    const float* vbase = isnew ? (vr + (size_t)bh * SS * DD)
                               : (vc + (size_t)(bh * KVC + ch * CK) * DD);

    s16x8 aq[4];
    {
        const float* qp = qr + (size_t)(bh * SS + r) * DD;
#pragma unroll
        for (int kk = 0; kk < 4; ++kk) {
            const float* p = qp + kk * 32 + g * 8;
            float4 x = *(const float4*)p;
            float4 y = *(const float4*)(p + 4);
            s16x8 a;
            a[0]=f2bf(x.x); a[1]=f2bf(x.y); a[2]=f2bf(x.z); a[3]=f2bf(x.w);
            a[4]=f2bf(y.x); a[5]=f2bf(y.y); a[6]=f2bf(y.z); a[7]=f2bf(y.w);
            aq[kk] = a;
        }
    }
    float mrow[4] = {-1e30f, -1e30f, -1e30f, -1e30f};
    float lrow[4] = {0.f, 0.f, 0.f, 0.f};
    f32x4 oacc[8];
#pragma unroll
    for (int nt = 0; nt < 8; ++nt) oacc[nt] = (f32x4){0.f, 0.f, 0.f, 0.f};

    __shared__ __align__(16) short Plds[16 * 32];

    int niter = isnew ? 1 : (CK / 32);
    for (int it = 0; it < niter; ++it) {
        int j0 = it * 32;
        f32x4 st[2];
        st[0] = (f32x4){0.f,0.f,0.f,0.f};
        st[1] = (f32x4){0.f,0.f,0.f,0.f};
#pragma unroll
        for (int t = 0; t < 2; ++t) {
            if (isnew && t == 1) continue;  // no keys there
            const float* kp = kbase + (size_t)(j0 + t * 16 + r) * DD;
#pragma unroll
            for (int kk = 0; kk < 4; ++kk) {
                const float* p = kp + kk * 32 + g * 8;
                float4 x = *(const float4*)p;
                float4 y = *(const float4*)(p + 4);
                s16x8 bk;
                bk[0]=f2bf(x.x); bk[1]=f2bf(x.y); bk[2]=f2bf(x.z); bk[3]=f2bf(x.w);
                bk[4]=f2bf(y.x); bk[5]=f2bf(y.y); bk[6]=f2bf(y.z); bk[7]=f2bf(y.w);
                st[t] = __builtin_amdgcn_mfma_f32_16x16x32_bf16(aq[kk], bk, st[t], 0, 0, 0);
            }
        }
#pragma unroll
        for (int t = 0; t < 2; ++t)
#pragma unroll
            for (int v = 0; v < 4; ++v) st[t][v] *= ATT_SCALE;
        if (isnew) {
#pragma unroll
            for (int v = 0; v < 4; ++v) {
                if (r > g * 4 + v) st[0][v] = -1e9f;  // causal over new keys
                st[1][v] = -1e9f;
            }
        }
        float mnew[4], corr[4];
#pragma unroll
        for (int v = 0; v < 4; ++v) {
            float x = fmaxf(st[0][v], st[1][v]);
            for (int msk = 1; msk < 16; msk <<= 1) x = fmaxf(x, __shfl_xor(x, msk));
            mnew[v] = fmaxf(mrow[v], x);
            corr[v] = __expf(mrow[v] - mnew[v]);
        }
#pragma unroll
        for (int t = 0; t < 2; ++t)
#pragma unroll
            for (int v = 0; v < 4; ++v) st[t][v] = __expf(st[t][v] - mnew[v]);
#pragma unroll
        for (int v = 0; v < 4; ++v) {
            float s = st[0][v] + st[1][v];
            for (int msk = 1; msk < 16; msk <<= 1) s += __shfl_xor(s, msk);
            lrow[v] = lrow[v] * corr[v] + s;
            mrow[v] = mnew[v];
        }
#pragma unroll
        for (int nt = 0; nt < 8; ++nt)
#pragma unroll
            for (int v = 0; v < 4; ++v) oacc[nt][v] *= corr[v];

        __syncthreads();
#pragma unroll
        for (int t = 0; t < 2; ++t)
#pragma unroll
            for (int v = 0; v < 4; ++v)
                Plds[(g * 4 + v) * 32 + t * 16 + r] = f2bf(st[t][v]);
        __syncthreads();
        s16x8 ap = *(const s16x8*)(Plds + r * 32 + g * 8);
#pragma unroll
        for (int nt = 0; nt < 8; ++nt) {
            s16x8 bv;
#pragma unroll
            for (int j = 0; j < 8; ++j) {
                int key = j0 + g * 8 + j;
                if (isnew && key > 15) key = 15;   // P==0 there; keep reads in-bounds/finite
                bv[j] = f2bf(vbase[(size_t)key * DD + nt * 16 + r]);
            }
            oacc[nt] = __builtin_amdgcn_mfma_f32_16x16x32_bf16(ap, bv, oacc[nt], 0, 0, 0);
        }
    }
    float* po = part_o + (size_t)(bh * NCH + ch) * SS * DD;
#pragma unroll
    for (int nt = 0; nt < 8; ++nt)
#pragma unroll
        for (int v = 0; v < 4; ++v)
            po[(size_t)(g * 4 + v) * DD + nt * 16 + r] = oacc[nt][v];
    if (r == 0) {
        float* pm = part_ml + (size_t)(bh * NCH + ch) * 32;
#pragma unroll
        for (int v = 0; v < 4; ++v) {
            pm[g * 4 + v] = mrow[v];
            pm[16 + g * 4 + v] = lrow[v];
        }
    }
}

// ---------------- Combine partials -> o_attn (b,s,h*d) --------------------------------
__global__ __launch_bounds__(128) void attn_comb_k(const float* __restrict__ part_o,
                                                   const float* __restrict__ part_ml,
                                                   float* __restrict__ oa) {
    int bh = blockIdx.x;
    int tid = threadIdx.x;
    __shared__ float sm[NCH * 16], sl[NCH * 16], sw[NCH * 16], sM[16], sLi[16];
    for (int i = tid; i < NCH * 16; i += 128) {
        const float* pm = part_ml + (size_t)(bh * NCH + (i >> 4)) * 32;
        sm[i] = pm[i & 15];
        sl[i] = pm[16 + (i & 15)];
    }
    __syncthreads();
    if (tid < 16) {
        float M = -1e30f;
        for (int c = 0; c < NCH; ++c) M = fmaxf(M, sm[c * 16 + tid]);
        float L = 0.f;
        for (int c = 0; c < NCH; ++c) L += sl[c * 16 + tid] * __expf(sm[c * 16 + tid] - M);
        sM[tid] = M;
        sLi[tid] = 1.f / L;
    }
    __syncthreads();
    for (int i = tid; i < NCH * 16; i += 128) sw[i] = __expf(sm[i] - sM[i & 15]);
    __syncthreads();
    int d = tid;                       // 0..127
    int b = bh / HH, h = bh % HH;
    for (int q = 0; q < 16; ++q) {
        float acc = 0.f;
        const float* po = part_o + (size_t)bh * NCH * SS * DD + (size_t)q * DD + d;
        for (int c = 0; c < NCH; ++c) acc += sw[c * 16 + q] * po[(size_t)c * SS * DD];
        oa[(size_t)(b * SS + q) * HIDN + h * DD + d] = acc * sLi[q];
    }
}

// ---------------- SwiGLU: f = silu(g) * u ---------------------------------------------
__global__ __launch_bounds__(256) void swiglu_k(const float* __restrict__ g,
                                                const float* __restrict__ u,
                                                float* __restrict__ f) {
    int i = blockIdx.x * 256 + threadIdx.x;
    float4 gv = ((const float4*)g)[i];
    float4 uv = ((const float4*)u)[i];
    float4 o;
    o.x = gv.x / (1.f + __expf(-gv.x)) * uv.x;
    o.y = gv.y / (1.f + __expf(-gv.y)) * uv.y;
    o.z = gv.z / (1.f + __expf(-gv.z)) * uv.z;
    o.w = gv.w / (1.f + __expf(-gv.w)) * uv.w;
    ((float4*)f)[i] = o;
}

extern "C" void kernel_launch(void* const* d_in, const int* in_sizes, int n_in,
                              void* d_out, int out_size, void* d_ws, size_t ws_size,
                              hipStream_t stream) {
    (void)in_sizes; (void)n_in; (void)out_size; (void)ws_size;
    const float* emb     = (const float*)d_in[0];
    // d_in[1] position_ids (== KV+s, baked in), d_in[2]/d_in[3] masks (structure baked in)
    const float* k_cache = (const float*)d_in[4];
    const float* v_cache = (const float*)d_in[5];
    const float* Wq = (const float*)d_in[6];
    const float* bq = (const float*)d_in[7];
    const float* Wk = (const float*)d_in[8];
    const float* bk = (const float*)d_in[9];
    const float* Wv = (const float*)d_in[10];
    const float* bv = (const float*)d_in[11];
    const float* Wo = (const float*)d_in[12];
    const float* Wg = (const float*)d_in[13];
    const float* Wu = (const float*)d_in[14];
    const float* Wd = (const float*)d_in[15];
    const float* ln1 = (const float*)d_in[16];
    const float* ln2 = (const float*)d_in[17];
    const float* normf = (const float*)d_in[18];
    float* out = (float*)d_out;

    float* ws = (float*)d_ws;
    const int TOK = BB * SS;                 // 256
    const size_t EMB_N = (size_t)TOK * HIDN; // 196608
    float* h  = ws;
    float* hn = h  + EMB_N;
    float* qb = hn + EMB_N;
    float* kb = qb + EMB_N;
    float* vb = kb + EMB_N;
    float* qr = vb + EMB_N;
    float* kr = qr + EMB_N;
    float* vr = kr + EMB_N;
    float* oa = vr + EMB_N;
    float* gb = oa + EMB_N;
    float* ub = gb + (size_t)TOK * FFN;
    float* fb = ub + (size_t)TOK * FFN;
    float* po = fb + (size_t)TOK * FFN;
    float* pml = po + (size_t)96 * NCH * SS * DD;

    hipMemcpyAsync(h, emb, EMB_N * sizeof(float), hipMemcpyDeviceToDevice, stream);

    const size_t WQKV = (size_t)HIDN * HH * DD;   // 589824
    const size_t WMLP = (size_t)HIDN * FFN;       // 1572864
    const size_t KVOFF = (size_t)BB * HH * KVC * DD;

    for (int l = 0; l < LNUM; ++l) {
        rmsnorm_k<<<TOK, 64, 0, stream>>>(h, ln1 + l * HIDN, hn);
        gemm_k<4, 0><<<dim3(48, 4, 3), 64, 0, stream>>>(hn,
            Wq + l * WQKV, Wk + l * WQKV, Wv + l * WQKV,
            bq + l * HH * DD, bk + l * HH * DD, bv + l * HH * DD,
            qb, kb, vb, HIDN, HH * DD);
        rope_k<<<dim3(TOK, HH), 64, 0, stream>>>(qb, kb, vb, qr, kr, vr);
        attn_part_k<<<dim3(BB * HH, NCH), 64, 0, stream>>>(qr, kr, vr,
            k_cache + (size_t)l * KVOFF, v_cache + (size_t)l * KVOFF, po, pml);
        attn_comb_k<<<BB * HH, 128, 0, stream>>>(po, pml, oa);
        gemm_k<4, 1><<<dim3(48, 4, 1), 64, 0, stream>>>(oa,
            Wo + l * WQKV, nullptr, nullptr, nullptr, nullptr, nullptr,
            h, nullptr, nullptr, HH * DD, HIDN);
        rmsnorm_k<<<TOK, 64, 0, stream>>>(h, ln2 + l * HIDN, hn);
        gemm_k<8, 0><<<dim3(FFN / 16, 2, 2), 64, 0, stream>>>(hn,
            Wg + l * WMLP, Wu + l * WMLP, nullptr,
            nullptr, nullptr, nullptr,
            gb, ub, nullptr, HIDN, FFN);
        swiglu_k<<<(TOK * FFN / 4) / 256, 256, 0, stream>>>(gb, ub, fb);
        gemm_k<4, 1><<<dim3(48, 4, 1), 64, 0, stream>>>(fb,
            Wd + l * WMLP, nullptr, nullptr, nullptr, nullptr, nullptr,
            h, nullptr, nullptr, FFN, HIDN);
    }
    rmsnorm_k<<<TOK, 64, 0, stream>>>(h, normf, out);
}

// Round 2
// 1240.900 us; speedup vs baseline: 1.3143x; 1.3143x over previous
//
#include <hip/hip_runtime.h>

#define LNUM 4
#define BB 16
#define SS 16
#define KVC 2048
#define HH 6
#define DD 128
#define HIDN 768
#define FFN 2048
#define NCH 9            // 8 cache chunks of 256 keys + 1 "new keys" chunk
#define ATT_SCALE 0.08838834764831845f

typedef unsigned short u16;
typedef short s16x8 __attribute__((ext_vector_type(8)));
typedef unsigned short u16x4 __attribute__((ext_vector_type(4)));
typedef float f32x4 __attribute__((ext_vector_type(4)));

__device__ __forceinline__ u16 f2bf(float f) {
    union { float f; unsigned u; } x; x.f = f;
    return (u16)((x.u + 0x7fffu + ((x.u >> 16) & 1u)) >> 16);
}

// ---------- weight transpose+convert: in f32 [K][N] -> out bf16 [N][K], per layer z ----
__global__ __launch_bounds__(256) void wtrans_k(const float* __restrict__ in,
                                                u16* __restrict__ out, int K, int N) {
    int n0 = blockIdx.x * 64, k0 = blockIdx.y * 64;
    size_t moff = (size_t)blockIdx.z * K * N;
    in += moff; out += moff;
    __shared__ __align__(16) u16 T[64][72];
    int t = threadIdx.x;
#pragma unroll
    for (int i = 0; i < 16; ++i) {
        int idx = i * 256 + t;
        int k = idx >> 6, n = idx & 63;
        T[k][n] = f2bf(in[(size_t)(k0 + k) * N + n0 + n]);
    }
    __syncthreads();
#pragma unroll
    for (int i = 0; i < 2; ++i) {
        int idx = i * 256 + t;
        int n = idx >> 3, kg = idx & 7;
        s16x8 v;
#pragma unroll
        for (int j = 0; j < 8; ++j) v[j] = (short)T[kg * 8 + j][n];
        *(s16x8*)(out + (size_t)(n0 + n) * K + k0 + kg * 8) = v;
    }
}

// ---------- RMSNorm: one wave per token row; OUTBF: write bf16 else f32 ---------------
template<int OUTBF>
__global__ __launch_bounds__(64) void rmsnorm_k(const float* __restrict__ x,
                                                const float* __restrict__ w,
                                                void* __restrict__ yv) {
    int row = blockIdx.x, lane = threadIdx.x;
    const float* xp = x + (size_t)row * HIDN + lane * 12;
    float4 a = *(const float4*)xp;
    float4 b = *(const float4*)(xp + 4);
    float4 c = *(const float4*)(xp + 8);
    float s = a.x*a.x + a.y*a.y + a.z*a.z + a.w*a.w
            + b.x*b.x + b.y*b.y + b.z*b.z + b.w*b.w
            + c.x*c.x + c.y*c.y + c.z*c.z + c.w*c.w;
    for (int m = 1; m < 64; m <<= 1) s += __shfl_xor(s, m);
    float rq = rsqrtf(s * (1.f / 768.f) + 1e-6f);
    const float* wp = w + lane * 12;
    float v[12];
#pragma unroll
    for (int i = 0; i < 4; ++i) { v[i]   = (&a.x)[i] * rq * wp[i]; }
#pragma unroll
    for (int i = 0; i < 4; ++i) { v[4+i] = (&b.x)[i] * rq * wp[4+i]; }
#pragma unroll
    for (int i = 0; i < 4; ++i) { v[8+i] = (&c.x)[i] * rq * wp[8+i]; }
    if (OUTBF) {
        u16* y = (u16*)yv + (size_t)row * HIDN + lane * 12;
#pragma unroll
        for (int i = 0; i < 3; ++i) {
            u16x4 o;
#pragma unroll
            for (int j = 0; j < 4; ++j) o[j] = f2bf(v[i * 4 + j]);
            *(u16x4*)(y + i * 4) = o;
        }
    } else {
        float* y = (float*)yv + (size_t)row * HIDN + lane * 12;
#pragma unroll
        for (int i = 0; i < 3; ++i) {
            float4 o; o.x = v[i*4]; o.y = v[i*4+1]; o.z = v[i*4+2]; o.w = v[i*4+3];
            *(float4*)(y + i * 4) = o;
        }
    }
}

// ---------- fused QKV GEMM + bias + rope -> qr/kr/vr bf16 (b,h,s,d) -------------------
// grid (18, 16): x = kind*6+h, y = b. One wave computes 16 tokens x 128 (full head).
__global__ __launch_bounds__(64) void qkv_k(const u16* __restrict__ hn,
                                            const u16* __restrict__ WqT, const u16* __restrict__ WkT,
                                            const u16* __restrict__ WvT,
                                            const float* __restrict__ bq, const float* __restrict__ bk,
                                            const float* __restrict__ bv,
                                            u16* __restrict__ qr, u16* __restrict__ kr,
                                            u16* __restrict__ vr) {
    int x = blockIdx.x, b = blockIdx.y;
    int kind = x / HH, h = x % HH;
    const u16* Wt = (kind == 0) ? WqT : (kind == 1) ? WkT : WvT;
    const float* bias = (kind == 0) ? bq : (kind == 1) ? bk : bv;
    u16* outp = (kind == 0) ? qr : (kind == 1) ? kr : vr;
    int lane = threadIdx.x, r = lane & 15, qg = lane >> 4;
    f32x4 acc[8];
#pragma unroll
    for (int nt = 0; nt < 8; ++nt) acc[nt] = (f32x4){0.f, 0.f, 0.f, 0.f};
    for (int k0 = 0; k0 < HIDN; k0 += 32) {
        s16x8 a = *(const s16x8*)(hn + (size_t)(b * 16 + r) * HIDN + k0 + qg * 8);
#pragma unroll
        for (int nt = 0; nt < 8; ++nt) {
            s16x8 bw = *(const s16x8*)(Wt + (size_t)(h * DD + nt * 16 + r) * HIDN + k0 + qg * 8);
            acc[nt] = __builtin_amdgcn_mfma_f32_16x16x32_bf16(a, bw, acc[nt], 0, 0, 0);
        }
    }
    int bh = b * HH + h;
    if (kind < 2) {
#pragma unroll
        for (int nt = 0; nt < 4; ++nt) {
            int d1 = nt * 16 + r, d2 = d1 + 64;
            float ts = powf(10000.f, (float)d1 * (1.f / 64.f));
            float b1 = bias[h * DD + d1], b2 = bias[h * DD + d2];
#pragma unroll
            for (int v = 0; v < 4; ++v) {
                int s = qg * 4 + v;
                float rad = (float)(KVC + s) / ts;
                float sn = sinf(rad), cs = cosf(rad);
                float x1 = acc[nt][v] + b1;
                float x2 = acc[nt + 4][v] + b2;
                outp[(size_t)(bh * 16 + s) * DD + d1] = f2bf(x1 * cs - x2 * sn);
                outp[(size_t)(bh * 16 + s) * DD + d2] = f2bf(x2 * cs + x1 * sn);
            }
        }
    } else {
#pragma unroll
        for (int nt = 0; nt < 8; ++nt) {
            int d = nt * 16 + r;
            float bb = bias[h * DD + d];
#pragma unroll
            for (int v = 0; v < 4; ++v)
                outp[(size_t)(bh * 16 + qg * 4 + v) * DD + d] = f2bf(acc[nt][v] + bb);
        }
    }
}

// ---------- attention partials: WG = 4 waves, (bh, 256-key chunk); LDS combine --------
__global__ __launch_bounds__(256) void attn_part_k(
    const u16* __restrict__ qr, const u16* __restrict__ kr, const u16* __restrict__ vr,
    const float* __restrict__ kc, const float* __restrict__ vc,
    float* __restrict__ part_o, float* __restrict__ part_ml) {
    int bh = blockIdx.x, ch = blockIdx.y;
    int tid = threadIdx.x, wid = tid >> 6, lane = tid & 63, r = lane & 15, qg = lane >> 4;
    bool isnew = (ch == NCH - 1);
    __shared__ __align__(16) u16 Plds[4][512];
    __shared__ float Osh[4][16][128];
    __shared__ float mlsh[4][32];

    s16x8 aq[4];
#pragma unroll
    for (int kk = 0; kk < 4; ++kk)
        aq[kk] = *(const s16x8*)(qr + (size_t)(bh * 16 + r) * DD + kk * 32 + qg * 8);

    float mrow[4] = {-1e30f, -1e30f, -1e30f, -1e30f};
    float lrow[4] = {0.f, 0.f, 0.f, 0.f};
    f32x4 oacc[8];
#pragma unroll
    for (int nt = 0; nt < 8; ++nt) oacc[nt] = (f32x4){0.f, 0.f, 0.f, 0.f};

    const float* kbase = kc + ((size_t)bh * KVC + ch * 256 + wid * 64) * DD;
    const float* vbase = vc + ((size_t)bh * KVC + ch * 256 + wid * 64) * DD;
    const u16* krn = kr + (size_t)bh * SS * DD;
    const u16* vrn = vr + (size_t)bh * SS * DD;

    int niter = isnew ? (wid == 0 ? 1 : 0) : 2;
    for (int it = 0; it < niter; ++it) {
        int j0 = it * 32;
        f32x4 st[2];
        st[0] = (f32x4){0.f,0.f,0.f,0.f};
        st[1] = (f32x4){0.f,0.f,0.f,0.f};
#pragma unroll
        for (int t = 0; t < 2; ++t) {
            if (isnew && t == 1) continue;
#pragma unroll
            for (int kk = 0; kk < 4; ++kk) {
                s16x8 bk;
                if (isnew) {
                    bk = *(const s16x8*)(krn + (size_t)(j0 + t * 16 + r) * DD + kk * 32 + qg * 8);
                } else {
                    const float* p = kbase + (size_t)(j0 + t * 16 + r) * DD + kk * 32 + qg * 8;
                    float4 xx = *(const float4*)p;
                    float4 yy = *(const float4*)(p + 4);
                    bk[0]=(short)f2bf(xx.x); bk[1]=(short)f2bf(xx.y); bk[2]=(short)f2bf(xx.z); bk[3]=(short)f2bf(xx.w);
                    bk[4]=(short)f2bf(yy.x); bk[5]=(short)f2bf(yy.y); bk[6]=(short)f2bf(yy.z); bk[7]=(short)f2bf(yy.w);
                }
                st[t] = __builtin_amdgcn_mfma_f32_16x16x32_bf16(aq[kk], bk, st[t], 0, 0, 0);
            }
        }
#pragma unroll
        for (int t = 0; t < 2; ++t)
#pragma unroll
            for (int v = 0; v < 4; ++v) st[t][v] *= ATT_SCALE;
        if (isnew) {
#pragma unroll
            for (int v = 0; v < 4; ++v) {
                if (r > qg * 4 + v) st[0][v] = -1e9f;
                st[1][v] = -1e9f;
            }
        }
        float mnew[4], corr[4];
#pragma unroll
        for (int v = 0; v < 4; ++v) {
            float xm = fmaxf(st[0][v], st[1][v]);
            for (int msk = 1; msk < 16; msk <<= 1) xm = fmaxf(xm, __shfl_xor(xm, msk));
            mnew[v] = fmaxf(mrow[v], xm);
            corr[v] = __expf(mrow[v] - mnew[v]);
        }
#pragma unroll
        for (int t = 0; t < 2; ++t)
#pragma unroll
            for (int v = 0; v < 4; ++v) st[t][v] = __expf(st[t][v] - mnew[v]);
#pragma unroll
        for (int v = 0; v < 4; ++v) {
            float ss = st[0][v] + st[1][v];
            for (int msk = 1; msk < 16; msk <<= 1) ss += __shfl_xor(ss, msk);
            lrow[v] = lrow[v] * corr[v] + ss;
            mrow[v] = mnew[v];
        }
#pragma unroll
        for (int nt = 0; nt < 8; ++nt)
#pragma unroll
            for (int v = 0; v < 4; ++v) oacc[nt][v] *= corr[v];

        // per-wave private LDS region: no barrier needed (same-wave RAW)
#pragma unroll
        for (int t = 0; t < 2; ++t)
#pragma unroll
            for (int v = 0; v < 4; ++v)
                Plds[wid][(qg * 4 + v) * 32 + t * 16 + r] = f2bf(st[t][v]);
        s16x8 ap = *(const s16x8*)(&Plds[wid][r * 32 + qg * 8]);
#pragma unroll
        for (int nt = 0; nt < 8; ++nt) {
            s16x8 bv;
#pragma unroll
            for (int j = 0; j < 8; ++j) {
                int key = j0 + qg * 8 + j;
                if (isnew) {
                    int kcl = key > 15 ? 15 : key;
                    bv[j] = (short)vrn[(size_t)kcl * DD + nt * 16 + r];
                } else {
                    bv[j] = (short)f2bf(vbase[(size_t)key * DD + nt * 16 + r]);
                }
            }
            oacc[nt] = __builtin_amdgcn_mfma_f32_16x16x32_bf16(ap, bv, oacc[nt], 0, 0, 0);
        }
    }
#pragma unroll
    for (int nt = 0; nt < 8; ++nt)
#pragma unroll
        for (int v = 0; v < 4; ++v)
            Osh[wid][qg * 4 + v][nt * 16 + r] = oacc[nt][v];
    if (r == 0) {
#pragma unroll
        for (int v = 0; v < 4; ++v) {
            mlsh[wid][qg * 4 + v] = mrow[v];
            mlsh[wid][16 + qg * 4 + v] = lrow[v];
        }
    }
    __syncthreads();
    int q = tid >> 4, dg = tid & 15;
    float M = -1e30f;
#pragma unroll
    for (int w = 0; w < 4; ++w) M = fmaxf(M, mlsh[w][q]);
    float L = 0.f, wgt[4];
#pragma unroll
    for (int w = 0; w < 4; ++w) {
        wgt[w] = __expf(mlsh[w][q] - M);
        L += mlsh[w][16 + q] * wgt[w];
    }
    float o[8];
#pragma unroll
    for (int j = 0; j < 8; ++j) o[j] = 0.f;
#pragma unroll
    for (int w = 0; w < 4; ++w)
#pragma unroll
        for (int j = 0; j < 8; ++j) o[j] += wgt[w] * Osh[w][q][dg * 8 + j];
    float* po = part_o + ((size_t)bh * NCH + ch) * (SS * DD) + q * DD + dg * 8;
    float4 o0; o0.x=o[0]; o0.y=o[1]; o0.z=o[2]; o0.w=o[3];
    float4 o1; o1.x=o[4]; o1.y=o[5]; o1.z=o[6]; o1.w=o[7];
    *(float4*)po = o0;
    *(float4*)(po + 4) = o1;
    if (dg == 0) {
        float* pm = part_ml + ((size_t)bh * NCH + ch) * 32;
        pm[q] = M;
        pm[16 + q] = L;
    }
}

// ---------- combine partials -> oa bf16 (b,s,h*d) -------------------------------------
__global__ __launch_bounds__(256) void attn_comb_k(const float* __restrict__ part_o,
                                                   const float* __restrict__ part_ml,
                                                   u16* __restrict__ oa) {
    int bh = blockIdx.x, tid = threadIdx.x;
    __shared__ float sw[NCH][16], sLi[16];
    if (tid < 16) {
        float M = -1e30f;
        for (int c = 0; c < NCH; ++c) M = fmaxf(M, part_ml[((size_t)bh * NCH + c) * 32 + tid]);
        float L = 0.f;
        for (int c = 0; c < NCH; ++c) {
            const float* pm = part_ml + ((size_t)bh * NCH + c) * 32;
            float w = __expf(pm[tid] - M);
            sw[c][tid] = w;
            L += pm[16 + tid] * w;
        }
        sLi[tid] = 1.f / L;
    }
    __syncthreads();
    int q = tid >> 4, dg = tid & 15;
    float o[8];
#pragma unroll
    for (int j = 0; j < 8; ++j) o[j] = 0.f;
    for (int c = 0; c < NCH; ++c) {
        const float* po = part_o + ((size_t)bh * NCH + c) * (SS * DD) + q * DD + dg * 8;
        float4 a = *(const float4*)po;
        float4 b = *(const float4*)(po + 4);
        float w = sw[c][q];
        o[0]+=w*a.x; o[1]+=w*a.y; o[2]+=w*a.z; o[3]+=w*a.w;
        o[4]+=w*b.x; o[5]+=w*b.y; o[6]+=w*b.z; o[7]+=w*b.w;
    }
    float inv = sLi[q];
    int b = bh / HH, h = bh % HH;
    u16* yp = oa + (size_t)(b * SS + q) * HIDN + h * DD + dg * 8;
    s16x8 ov;
#pragma unroll
    for (int j = 0; j < 8; ++j) ov[j] = (short)f2bf(o[j] * inv);
    *(s16x8*)yp = ov;
}

// ---------- GEMM with residual: H[256][768] += A[256][K] @ Wt^T ------------------------
__global__ __launch_bounds__(64) void gemm_res_k(const u16* __restrict__ A,
                                                 const u16* __restrict__ Wt,
                                                 float* __restrict__ H, int K) {
    int lane = threadIdx.x, r = lane & 15, qg = lane >> 4;
    int n0 = blockIdx.x * 64, m0 = blockIdx.y * 16;
    f32x4 acc[4];
#pragma unroll
    for (int nt = 0; nt < 4; ++nt) acc[nt] = (f32x4){0.f, 0.f, 0.f, 0.f};
    for (int k0 = 0; k0 < K; k0 += 32) {
        s16x8 a = *(const s16x8*)(A + (size_t)(m0 + r) * K + k0 + qg * 8);
#pragma unroll
        for (int nt = 0; nt < 4; ++nt) {
            s16x8 bw = *(const s16x8*)(Wt + (size_t)(n0 + nt * 16 + r) * K + k0 + qg * 8);
            acc[nt] = __builtin_amdgcn_mfma_f32_16x16x32_bf16(a, bw, acc[nt], 0, 0, 0);
        }
    }
#pragma unroll
    for (int nt = 0; nt < 4; ++nt)
#pragma unroll
        for (int v = 0; v < 4; ++v)
            H[(size_t)(m0 + qg * 4 + v) * HIDN + n0 + nt * 16 + r] += acc[nt][v];
}

// ---------- fused gate/up GEMM + SwiGLU -> fb bf16 [256][2048] -------------------------
__global__ __launch_bounds__(64) void gemm_gu_k(const u16* __restrict__ A,
                                                const u16* __restrict__ WgT,
                                                const u16* __restrict__ WuT,
                                                u16* __restrict__ F) {
    int lane = threadIdx.x, r = lane & 15, qg = lane >> 4;
    int n0 = blockIdx.x * 64, m0 = blockIdx.y * 16;
    f32x4 ag[4], au[4];
#pragma unroll
    for (int nt = 0; nt < 4; ++nt) {
        ag[nt] = (f32x4){0.f, 0.f, 0.f, 0.f};
        au[nt] = (f32x4){0.f, 0.f, 0.f, 0.f};
    }
    for (int k0 = 0; k0 < HIDN; k0 += 32) {
        s16x8 a = *(const s16x8*)(A + (size_t)(m0 + r) * HIDN + k0 + qg * 8);
#pragma unroll
        for (int nt = 0; nt < 4; ++nt) {
            s16x8 bg = *(const s16x8*)(WgT + (size_t)(n0 + nt * 16 + r) * HIDN + k0 + qg * 8);
            ag[nt] = __builtin_amdgcn_mfma_f32_16x16x32_bf16(a, bg, ag[nt], 0, 0, 0);
            s16x8 bu = *(const s16x8*)(WuT + (size_t)(n0 + nt * 16 + r) * HIDN + k0 + qg * 8);
            au[nt] = __builtin_amdgcn_mfma_f32_16x16x32_bf16(a, bu, au[nt], 0, 0, 0);
        }
    }
#pragma unroll
    for (int nt = 0; nt < 4; ++nt)
#pragma unroll
        for (int v = 0; v < 4; ++v) {
            float gv = ag[nt][v], uv = au[nt][v];
            float f = gv / (1.f + __expf(-gv)) * uv;
            F[(size_t)(m0 + qg * 4 + v) * FFN + n0 + nt * 16 + r] = f2bf(f);
        }
}

extern "C" void kernel_launch(void* const* d_in, const int* in_sizes, int n_in,
                              void* d_out, int out_size, void* d_ws, size_t ws_size,
                              hipStream_t stream) {
    (void)in_sizes; (void)n_in; (void)out_size; (void)ws_size;
    const float* emb     = (const float*)d_in[0];
    const float* k_cache = (const float*)d_in[4];
    const float* v_cache = (const float*)d_in[5];
    const float* Wq = (const float*)d_in[6];
    const float* bq = (const float*)d_in[7];
    const float* Wk = (const float*)d_in[8];
    const float* bk = (const float*)d_in[9];
    const float* Wv = (const float*)d_in[10];
    const float* bv = (const float*)d_in[11];
    const float* Wo = (const float*)d_in[12];
    const float* Wg = (const float*)d_in[13];
    const float* Wu = (const float*)d_in[14];
    const float* Wd = (const float*)d_in[15];
    const float* ln1 = (const float*)d_in[16];
    const float* ln2 = (const float*)d_in[17];
    const float* normf = (const float*)d_in[18];
    float* out = (float*)d_out;

    char* p = (char*)d_ws;
    auto alloc = [&](size_t bytes) { void* r = p; p += (bytes + 255) & ~255ull; return r; };
    const size_t WQKV = (size_t)HIDN * HH * DD;   // 589824
    const size_t WMLP = (size_t)HIDN * FFN;       // 1572864
    u16* WqT = (u16*)alloc(LNUM * WQKV * 2);
    u16* WkT = (u16*)alloc(LNUM * WQKV * 2);
    u16* WvT = (u16*)alloc(LNUM * WQKV * 2);
    u16* WoT = (u16*)alloc(LNUM * WQKV * 2);
    u16* WgT = (u16*)alloc(LNUM * WMLP * 2);
    u16* WuT = (u16*)alloc(LNUM * WMLP * 2);
    u16* WdT = (u16*)alloc(LNUM * WMLP * 2);
    const int TOK = BB * SS;
    const size_t EMB_N = (size_t)TOK * HIDN;
    float* h  = (float*)alloc(EMB_N * 4);
    u16* hn   = (u16*)alloc(EMB_N * 2);
    u16* qr   = (u16*)alloc((size_t)BB * HH * SS * DD * 2);
    u16* kr   = (u16*)alloc((size_t)BB * HH * SS * DD * 2);
    u16* vr   = (u16*)alloc((size_t)BB * HH * SS * DD * 2);
    u16* oa   = (u16*)alloc(EMB_N * 2);
    u16* fb   = (u16*)alloc((size_t)TOK * FFN * 2);
    float* po  = (float*)alloc((size_t)96 * NCH * SS * DD * 4);
    float* pml = (float*)alloc((size_t)96 * NCH * 32 * 4);

    // one-time weight transpose+convert (per call)
    wtrans_k<<<dim3(12, 12, LNUM), 256, 0, stream>>>(Wq, WqT, HIDN, HH * DD);
    wtrans_k<<<dim3(12, 12, LNUM), 256, 0, stream>>>(Wk, WkT, HIDN, HH * DD);
    wtrans_k<<<dim3(12, 12, LNUM), 256, 0, stream>>>(Wv, WvT, HIDN, HH * DD);
    wtrans_k<<<dim3(12, 12, LNUM), 256, 0, stream>>>(Wo, WoT, HH * DD, HIDN);
    wtrans_k<<<dim3(32, 12, LNUM), 256, 0, stream>>>(Wg, WgT, HIDN, FFN);
    wtrans_k<<<dim3(32, 12, LNUM), 256, 0, stream>>>(Wu, WuT, HIDN, FFN);
    wtrans_k<<<dim3(12, 32, LNUM), 256, 0, stream>>>(Wd, WdT, FFN, HIDN);

    hipMemcpyAsync(h, emb, EMB_N * sizeof(float), hipMemcpyDeviceToDevice, stream);

    const size_t KVOFF = (size_t)BB * HH * KVC * DD;
    for (int l = 0; l < LNUM; ++l) {
        rmsnorm_k<1><<<TOK, 64, 0, stream>>>(h, ln1 + l * HIDN, hn);
        qkv_k<<<dim3(3 * HH, BB), 64, 0, stream>>>(hn,
            WqT + l * WQKV, WkT + l * WQKV, WvT + l * WQKV,
            bq + l * HH * DD, bk + l * HH * DD, bv + l * HH * DD, qr, kr, vr);
        attn_part_k<<<dim3(BB * HH, NCH), 256, 0, stream>>>(qr, kr, vr,
            k_cache + (size_t)l * KVOFF, v_cache + (size_t)l * KVOFF, po, pml);
        attn_comb_k<<<BB * HH, 256, 0, stream>>>(po, pml, oa);
        gemm_res_k<<<dim3(12, 16), 64, 0, stream>>>(oa, WoT + l * WQKV, h, HH * DD);
        rmsnorm_k<1><<<TOK, 64, 0, stream>>>(h, ln2 + l * HIDN, hn);
        gemm_gu_k<<<dim3(32, 16), 64, 0, stream>>>(hn, WgT + l * WMLP, WuT + l * WMLP, fb);
        gemm_res_k<<<dim3(12, 16), 64, 0, stream>>>(fb, WdT + l * WMLP, h, FFN);
    }
    rmsnorm_k<0><<<TOK, 64, 0, stream>>>(h, normf, out);
}

// Round 3
// 886.466 us; speedup vs baseline: 1.8398x; 1.3998x over previous
//
#include <hip/hip_runtime.h>
#include <hip/hip_bf16.h>

#define LNUM 4
#define BB 16
#define SS 16
#define KVC 2048
#define HH 6
#define DD 128
#define HIDN 768
#define FFN 2048
#define NCH 17           // 16 cache chunks of 128 keys + 1 "new keys" chunk
#define ATT_SCALE 0.08838834764831845f

typedef unsigned short u16;
typedef short s16x8 __attribute__((ext_vector_type(8)));
typedef unsigned short u16x4 __attribute__((ext_vector_type(4)));
typedef float f32x4 __attribute__((ext_vector_type(4)));

__device__ __forceinline__ short f2bfs(float f) {
    __hip_bfloat16 h = __float2bfloat16(f);   // RNE; compiler pairs into v_cvt_pk_bf16_f32
    return *reinterpret_cast<short*>(&h);
}

// ---------- weight transpose+convert: in f32 [K][N] -> out bf16 [N][K], per layer z ----
__global__ __launch_bounds__(256) void wtrans_k(const float* __restrict__ in,
                                                u16* __restrict__ out, int K, int N) {
    int n0 = blockIdx.x * 64, k0 = blockIdx.y * 64;
    size_t moff = (size_t)blockIdx.z * K * N;
    in += moff; out += moff;
    __shared__ __align__(16) u16 T[64][72];
    int t = threadIdx.x;
#pragma unroll
    for (int i = 0; i < 16; ++i) {
        int idx = i * 256 + t;
        int k = idx >> 6, n = idx & 63;
        T[k][n] = (u16)f2bfs(in[(size_t)(k0 + k) * N + n0 + n]);
    }
    __syncthreads();
#pragma unroll
    for (int i = 0; i < 2; ++i) {
        int idx = i * 256 + t;
        int n = idx >> 3, kg = idx & 7;
        s16x8 v;
#pragma unroll
        for (int j = 0; j < 8; ++j) v[j] = (short)T[kg * 8 + j][n];
        *(s16x8*)(out + (size_t)(n0 + n) * K + k0 + kg * 8) = v;
    }
}

// ---------- RMSNorm: one wave per token row; OUTBF: write bf16 else f32 ---------------
template<int OUTBF>
__global__ __launch_bounds__(64) void rmsnorm_k(const float* __restrict__ x,
                                                const float* __restrict__ w,
                                                void* __restrict__ yv) {
    int row = blockIdx.x, lane = threadIdx.x;
    const float* xp = x + (size_t)row * HIDN + lane * 12;
    float4 a = *(const float4*)xp;
    float4 b = *(const float4*)(xp + 4);
    float4 c = *(const float4*)(xp + 8);
    float s = a.x*a.x + a.y*a.y + a.z*a.z + a.w*a.w
            + b.x*b.x + b.y*b.y + b.z*b.z + b.w*b.w
            + c.x*c.x + c.y*c.y + c.z*c.z + c.w*c.w;
    for (int m = 1; m < 64; m <<= 1) s += __shfl_xor(s, m);
    float rq = rsqrtf(s * (1.f / 768.f) + 1e-6f);
    const float* wp = w + lane * 12;
    float v[12];
#pragma unroll
    for (int i = 0; i < 4; ++i) { v[i]   = (&a.x)[i] * rq * wp[i]; }
#pragma unroll
    for (int i = 0; i < 4; ++i) { v[4+i] = (&b.x)[i] * rq * wp[4+i]; }
#pragma unroll
    for (int i = 0; i < 4; ++i) { v[8+i] = (&c.x)[i] * rq * wp[8+i]; }
    if (OUTBF) {
        u16* y = (u16*)yv + (size_t)row * HIDN + lane * 12;
#pragma unroll
        for (int i = 0; i < 3; ++i) {
            u16x4 o;
#pragma unroll
            for (int j = 0; j < 4; ++j) o[j] = (u16)f2bfs(v[i * 4 + j]);
            *(u16x4*)(y + i * 4) = o;
        }
    } else {
        float* y = (float*)yv + (size_t)row * HIDN + lane * 12;
#pragma unroll
        for (int i = 0; i < 3; ++i) {
            float4 o; o.x = v[i*4]; o.y = v[i*4+1]; o.z = v[i*4+2]; o.w = v[i*4+3];
            *(float4*)(y + i * 4) = o;
        }
    }
}

// ---------- fused QKV GEMM + bias + rope -> qr/kr/vr bf16 (b,h,s,d) -------------------
__global__ __launch_bounds__(64) void qkv_k(const u16* __restrict__ hn,
                                            const u16* __restrict__ WqT, const u16* __restrict__ WkT,
                                            const u16* __restrict__ WvT,
                                            const float* __restrict__ bq, const float* __restrict__ bk,
                                            const float* __restrict__ bv,
                                            u16* __restrict__ qr, u16* __restrict__ kr,
                                            u16* __restrict__ vr) {
    int x = blockIdx.x, b = blockIdx.y;
    int kind = x / HH, h = x % HH;
    const u16* Wt = (kind == 0) ? WqT : (kind == 1) ? WkT : WvT;
    const float* bias = (kind == 0) ? bq : (kind == 1) ? bk : bv;
    u16* outp = (kind == 0) ? qr : (kind == 1) ? kr : vr;
    int lane = threadIdx.x, r = lane & 15, qg = lane >> 4;
    f32x4 acc[8];
#pragma unroll
    for (int nt = 0; nt < 8; ++nt) acc[nt] = (f32x4){0.f, 0.f, 0.f, 0.f};
#pragma unroll 2
    for (int k0 = 0; k0 < HIDN; k0 += 32) {
        s16x8 a = *(const s16x8*)(hn + (size_t)(b * 16 + r) * HIDN + k0 + qg * 8);
#pragma unroll
        for (int nt = 0; nt < 8; ++nt) {
            s16x8 bw = *(const s16x8*)(Wt + (size_t)(h * DD + nt * 16 + r) * HIDN + k0 + qg * 8);
            acc[nt] = __builtin_amdgcn_mfma_f32_16x16x32_bf16(a, bw, acc[nt], 0, 0, 0);
        }
    }
    int bh = b * HH + h;
    if (kind < 2) {
#pragma unroll
        for (int nt = 0; nt < 4; ++nt) {
            int d1 = nt * 16 + r, d2 = d1 + 64;
            float ts = powf(10000.f, (float)d1 * (1.f / 64.f));
            float b1 = bias[h * DD + d1], b2 = bias[h * DD + d2];
#pragma unroll
            for (int v = 0; v < 4; ++v) {
                int s = qg * 4 + v;
                float rad = (float)(KVC + s) / ts;
                float sn = sinf(rad), cs = cosf(rad);
                float x1 = acc[nt][v] + b1;
                float x2 = acc[nt + 4][v] + b2;
                outp[(size_t)(bh * 16 + s) * DD + d1] = (u16)f2bfs(x1 * cs - x2 * sn);
                outp[(size_t)(bh * 16 + s) * DD + d2] = (u16)f2bfs(x2 * cs + x1 * sn);
            }
        }
    } else {
#pragma unroll
        for (int nt = 0; nt < 8; ++nt) {
            int d = nt * 16 + r;
            float bb = bias[h * DD + d];
#pragma unroll
            for (int v = 0; v < 4; ++v)
                outp[(size_t)(bh * 16 + qg * 4 + v) * DD + d] = (u16)f2bfs(acc[nt][v] + bb);
        }
    }
}

// ---------- attention partials: WG = 4 waves, 128 keys/WG, single pass per wave -------
__global__ __launch_bounds__(256) void attn_part_k(
    const u16* __restrict__ qr, const u16* __restrict__ kr, const u16* __restrict__ vr,
    const float* __restrict__ kc, const float* __restrict__ vc,
    float* __restrict__ part_o, float* __restrict__ part_ml) {
    int bh = blockIdx.x, ch = blockIdx.y;
    int tid = threadIdx.x, wid = tid >> 6, lane = tid & 63, r = lane & 15, qg = lane >> 4;
    bool isnew = (ch == NCH - 1);
    bool active = !isnew || (wid == 0);
    __shared__ __align__(16) u16 Plds[4][512];
    __shared__ float Osh[4][16][128];
    __shared__ float mlsh[4][32];

    float mrow[4] = {-1e30f, -1e30f, -1e30f, -1e30f};
    float lrow[4] = {0.f, 0.f, 0.f, 0.f};
    f32x4 oacc[8];
#pragma unroll
    for (int nt = 0; nt < 8; ++nt) oacc[nt] = (f32x4){0.f, 0.f, 0.f, 0.f};

    if (active) {
        s16x8 aq[4];
#pragma unroll
        for (int kk = 0; kk < 4; ++kk)
            aq[kk] = *(const s16x8*)(qr + (size_t)(bh * 16 + r) * DD + kk * 32 + qg * 8);
        const float* kbase = kc + ((size_t)bh * KVC + ch * 128 + wid * 32) * DD;
        const float* vbase = vc + ((size_t)bh * KVC + ch * 128 + wid * 32) * DD;
        const u16* krn = kr + (size_t)bh * SS * DD;
        const u16* vrn = vr + (size_t)bh * SS * DD;

        f32x4 st[2];
        st[0] = (f32x4){0.f,0.f,0.f,0.f};
        st[1] = (f32x4){0.f,0.f,0.f,0.f};
#pragma unroll
        for (int t = 0; t < 2; ++t) {
            if (isnew && t == 1) continue;
#pragma unroll
            for (int kk = 0; kk < 4; ++kk) {
                s16x8 bk;
                if (isnew) {
                    bk = *(const s16x8*)(krn + (size_t)(t * 16 + r) * DD + kk * 32 + qg * 8);
                } else {
                    const float* p = kbase + (size_t)(t * 16 + r) * DD + kk * 32 + qg * 8;
                    float4 xx = *(const float4*)p;
                    float4 yy = *(const float4*)(p + 4);
                    bk[0]=f2bfs(xx.x); bk[1]=f2bfs(xx.y); bk[2]=f2bfs(xx.z); bk[3]=f2bfs(xx.w);
                    bk[4]=f2bfs(yy.x); bk[5]=f2bfs(yy.y); bk[6]=f2bfs(yy.z); bk[7]=f2bfs(yy.w);
                }
                st[t] = __builtin_amdgcn_mfma_f32_16x16x32_bf16(aq[kk], bk, st[t], 0, 0, 0);
            }
        }
#pragma unroll
        for (int t = 0; t < 2; ++t)
#pragma unroll
            for (int v = 0; v < 4; ++v) st[t][v] *= ATT_SCALE;
        if (isnew) {
#pragma unroll
            for (int v = 0; v < 4; ++v) {
                if (r > qg * 4 + v) st[0][v] = -1e9f;
                st[1][v] = -1e9f;
            }
        }
#pragma unroll
        for (int v = 0; v < 4; ++v) {
            float xm = fmaxf(st[0][v], st[1][v]);
            for (int msk = 1; msk < 16; msk <<= 1) xm = fmaxf(xm, __shfl_xor(xm, msk));
            mrow[v] = xm;
        }
#pragma unroll
        for (int t = 0; t < 2; ++t)
#pragma unroll
            for (int v = 0; v < 4; ++v) st[t][v] = __expf(st[t][v] - mrow[v]);
#pragma unroll
        for (int v = 0; v < 4; ++v) {
            float ss = st[0][v] + st[1][v];
            for (int msk = 1; msk < 16; msk <<= 1) ss += __shfl_xor(ss, msk);
            lrow[v] = ss;
        }
        // P -> bf16 via per-wave LDS bounce (same-wave RAW, no barrier)
#pragma unroll
        for (int t = 0; t < 2; ++t)
#pragma unroll
            for (int v = 0; v < 4; ++v)
                Plds[wid][(qg * 4 + v) * 32 + t * 16 + r] = (u16)f2bfs(st[t][v]);
        s16x8 ap = *(const s16x8*)(&Plds[wid][r * 32 + qg * 8]);
#pragma unroll
        for (int nt = 0; nt < 8; ++nt) {
            s16x8 bv;
#pragma unroll
            for (int j = 0; j < 8; ++j) {
                int key = qg * 8 + j;
                if (isnew) {
                    int kcl = key > 15 ? 15 : key;
                    bv[j] = (short)vrn[(size_t)kcl * DD + nt * 16 + r];
                } else {
                    bv[j] = f2bfs(vbase[(size_t)key * DD + nt * 16 + r]);
                }
            }
            oacc[nt] = __builtin_amdgcn_mfma_f32_16x16x32_bf16(ap, bv, oacc[nt], 0, 0, 0);
        }
    }
#pragma unroll
    for (int nt = 0; nt < 8; ++nt)
#pragma unroll
        for (int v = 0; v < 4; ++v)
            Osh[wid][qg * 4 + v][nt * 16 + r] = oacc[nt][v];
    if (r == 0) {
#pragma unroll
        for (int v = 0; v < 4; ++v) {
            mlsh[wid][qg * 4 + v] = mrow[v];
            mlsh[wid][16 + qg * 4 + v] = lrow[v];
        }
    }
    __syncthreads();
    int q = tid >> 4, dg = tid & 15;
    float M = -1e30f;
#pragma unroll
    for (int w = 0; w < 4; ++w) M = fmaxf(M, mlsh[w][q]);
    float L = 0.f, wgt[4];
#pragma unroll
    for (int w = 0; w < 4; ++w) {
        wgt[w] = __expf(mlsh[w][q] - M);
        L += mlsh[w][16 + q] * wgt[w];
    }
    float o[8];
#pragma unroll
    for (int j = 0; j < 8; ++j) o[j] = 0.f;
#pragma unroll
    for (int w = 0; w < 4; ++w)
#pragma unroll
        for (int j = 0; j < 8; ++j) o[j] += wgt[w] * Osh[w][q][dg * 8 + j];
    float* po = part_o + ((size_t)bh * NCH + ch) * (SS * DD) + q * DD + dg * 8;
    float4 o0; o0.x=o[0]; o0.y=o[1]; o0.z=o[2]; o0.w=o[3];
    float4 o1; o1.x=o[4]; o1.y=o[5]; o1.z=o[6]; o1.w=o[7];
    *(float4*)po = o0;
    *(float4*)(po + 4) = o1;
    if (dg == 0) {
        float* pm = part_ml + ((size_t)bh * NCH + ch) * 32;
        pm[q] = M;
        pm[16 + q] = L;
    }
}

// ---------- combine partials -> oa bf16 (b,s,h*d) -------------------------------------
__global__ __launch_bounds__(256) void attn_comb_k(const float* __restrict__ part_o,
                                                   const float* __restrict__ part_ml,
                                                   u16* __restrict__ oa) {
    int bh = blockIdx.x, tid = threadIdx.x;
    __shared__ float sw[NCH][16], sLi[16];
    if (tid < 16) {
        float M = -1e30f;
        for (int c = 0; c < NCH; ++c) M = fmaxf(M, part_ml[((size_t)bh * NCH + c) * 32 + tid]);
        float L = 0.f;
        for (int c = 0; c < NCH; ++c) {
            const float* pm = part_ml + ((size_t)bh * NCH + c) * 32;
            float w = __expf(pm[tid] - M);
            sw[c][tid] = w;
            L += pm[16 + tid] * w;
        }
        sLi[tid] = 1.f / L;
    }
    __syncthreads();
    int q = tid >> 4, dg = tid & 15;
    float o[8];
#pragma unroll
    for (int j = 0; j < 8; ++j) o[j] = 0.f;
    for (int c = 0; c < NCH; ++c) {
        const float* po = part_o + ((size_t)bh * NCH + c) * (SS * DD) + q * DD + dg * 8;
        float4 a = *(const float4*)po;
        float4 b = *(const float4*)(po + 4);
        float w = sw[c][q];
        o[0]+=w*a.x; o[1]+=w*a.y; o[2]+=w*a.z; o[3]+=w*a.w;
        o[4]+=w*b.x; o[5]+=w*b.y; o[6]+=w*b.z; o[7]+=w*b.w;
    }
    float inv = sLi[q];
    int b = bh / HH, h = bh % HH;
    u16* yp = oa + (size_t)(b * SS + q) * HIDN + h * DD + dg * 8;
    s16x8 ov;
#pragma unroll
    for (int j = 0; j < 8; ++j) ov[j] = f2bfs(o[j] * inv);
    *(s16x8*)yp = ov;
}

// ---------- GEMM with residual: H[256][768] += A[256][K] @ Wt^T ------------------------
template<int K>
__global__ __launch_bounds__(64) void gemm_res_k(const u16* __restrict__ A,
                                                 const u16* __restrict__ Wt,
                                                 float* __restrict__ H) {
    int lane = threadIdx.x, r = lane & 15, qg = lane >> 4;
    int n0 = blockIdx.x * 64, m0 = blockIdx.y * 16;
    f32x4 acc[4];
#pragma unroll
    for (int nt = 0; nt < 4; ++nt) acc[nt] = (f32x4){0.f, 0.f, 0.f, 0.f};
#pragma unroll 4
    for (int k0 = 0; k0 < K; k0 += 32) {
        s16x8 a = *(const s16x8*)(A + (size_t)(m0 + r) * K + k0 + qg * 8);
#pragma unroll
        for (int nt = 0; nt < 4; ++nt) {
            s16x8 bw = *(const s16x8*)(Wt + (size_t)(n0 + nt * 16 + r) * K + k0 + qg * 8);
            acc[nt] = __builtin_amdgcn_mfma_f32_16x16x32_bf16(a, bw, acc[nt], 0, 0, 0);
        }
    }
#pragma unroll
    for (int nt = 0; nt < 4; ++nt)
#pragma unroll
        for (int v = 0; v < 4; ++v)
            H[(size_t)(m0 + qg * 4 + v) * HIDN + n0 + nt * 16 + r] += acc[nt][v];
}

// ---------- fused gate/up GEMM + SwiGLU -> fb bf16 [256][2048] -------------------------
__global__ __launch_bounds__(64) void gemm_gu_k(const u16* __restrict__ A,
                                                const u16* __restrict__ WgT,
                                                const u16* __restrict__ WuT,
                                                u16* __restrict__ F) {
    int lane = threadIdx.x, r = lane & 15, qg = lane >> 4;
    int n0 = blockIdx.x * 64, m0 = blockIdx.y * 16;
    f32x4 ag[4], au[4];
#pragma unroll
    for (int nt = 0; nt < 4; ++nt) {
        ag[nt] = (f32x4){0.f, 0.f, 0.f, 0.f};
        au[nt] = (f32x4){0.f, 0.f, 0.f, 0.f};
    }
#pragma unroll 2
    for (int k0 = 0; k0 < HIDN; k0 += 32) {
        s16x8 a = *(const s16x8*)(A + (size_t)(m0 + r) * HIDN + k0 + qg * 8);
#pragma unroll
        for (int nt = 0; nt < 4; ++nt) {
            s16x8 bg = *(const s16x8*)(WgT + (size_t)(n0 + nt * 16 + r) * HIDN + k0 + qg * 8);
            ag[nt] = __builtin_amdgcn_mfma_f32_16x16x32_bf16(a, bg, ag[nt], 0, 0, 0);
            s16x8 bu = *(const s16x8*)(WuT + (size_t)(n0 + nt * 16 + r) * HIDN + k0 + qg * 8);
            au[nt] = __builtin_amdgcn_mfma_f32_16x16x32_bf16(a, bu, au[nt], 0, 0, 0);
        }
    }
#pragma unroll
    for (int nt = 0; nt < 4; ++nt)
#pragma unroll
        for (int v = 0; v < 4; ++v) {
            float gv = ag[nt][v], uv = au[nt][v];
            float f = gv / (1.f + __expf(-gv)) * uv;
            F[(size_t)(m0 + qg * 4 + v) * FFN + n0 + nt * 16 + r] = (u16)f2bfs(f);
        }
}

extern "C" void kernel_launch(void* const* d_in, const int* in_sizes, int n_in,
                              void* d_out, int out_size, void* d_ws, size_t ws_size,
                              hipStream_t stream) {
    (void)in_sizes; (void)n_in; (void)out_size; (void)ws_size;
    const float* emb     = (const float*)d_in[0];
    const float* k_cache = (const float*)d_in[4];
    const float* v_cache = (const float*)d_in[5];
    const float* Wq = (const float*)d_in[6];
    const float* bq = (const float*)d_in[7];
    const float* Wk = (const float*)d_in[8];
    const float* bk = (const float*)d_in[9];
    const float* Wv = (const float*)d_in[10];
    const float* bv = (const float*)d_in[11];
    const float* Wo = (const float*)d_in[12];
    const float* Wg = (const float*)d_in[13];
    const float* Wu = (const float*)d_in[14];
    const float* Wd = (const float*)d_in[15];
    const float* ln1 = (const float*)d_in[16];
    const float* ln2 = (const float*)d_in[17];
    const float* normf = (const float*)d_in[18];
    float* out = (float*)d_out;

    char* p = (char*)d_ws;
    auto alloc = [&](size_t bytes) { void* r = p; p += (bytes + 255) & ~255ull; return r; };
    const size_t WQKV = (size_t)HIDN * HH * DD;   // 589824
    const size_t WMLP = (size_t)HIDN * FFN;       // 1572864
    u16* WqT = (u16*)alloc(LNUM * WQKV * 2);
    u16* WkT = (u16*)alloc(LNUM * WQKV * 2);
    u16* WvT = (u16*)alloc(LNUM * WQKV * 2);
    u16* WoT = (u16*)alloc(LNUM * WQKV * 2);
    u16* WgT = (u16*)alloc(LNUM * WMLP * 2);
    u16* WuT = (u16*)alloc(LNUM * WMLP * 2);
    u16* WdT = (u16*)alloc(LNUM * WMLP * 2);
    const int TOK = BB * SS;
    const size_t EMB_N = (size_t)TOK * HIDN;
    float* h  = (float*)alloc(EMB_N * 4);
    u16* hn   = (u16*)alloc(EMB_N * 2);
    u16* qr   = (u16*)alloc((size_t)BB * HH * SS * DD * 2);
    u16* kr   = (u16*)alloc((size_t)BB * HH * SS * DD * 2);
    u16* vr   = (u16*)alloc((size_t)BB * HH * SS * DD * 2);
    u16* oa   = (u16*)alloc(EMB_N * 2);
    u16* fb   = (u16*)alloc((size_t)TOK * FFN * 2);
    float* po  = (float*)alloc((size_t)96 * NCH * SS * DD * 4);
    float* pml = (float*)alloc((size_t)96 * NCH * 32 * 4);

    // one-time weight transpose+convert (per call)
    wtrans_k<<<dim3(12, 12, LNUM), 256, 0, stream>>>(Wq, WqT, HIDN, HH * DD);
    wtrans_k<<<dim3(12, 12, LNUM), 256, 0, stream>>>(Wk, WkT, HIDN, HH * DD);
    wtrans_k<<<dim3(12, 12, LNUM), 256, 0, stream>>>(Wv, WvT, HIDN, HH * DD);
    wtrans_k<<<dim3(12, 12, LNUM), 256, 0, stream>>>(Wo, WoT, HH * DD, HIDN);
    wtrans_k<<<dim3(32, 12, LNUM), 256, 0, stream>>>(Wg, WgT, HIDN, FFN);
    wtrans_k<<<dim3(32, 12, LNUM), 256, 0, stream>>>(Wu, WuT, HIDN, FFN);
    wtrans_k<<<dim3(12, 32, LNUM), 256, 0, stream>>>(Wd, WdT, FFN, HIDN);

    hipMemcpyAsync(h, emb, EMB_N * sizeof(float), hipMemcpyDeviceToDevice, stream);

    const size_t KVOFF = (size_t)BB * HH * KVC * DD;
    for (int l = 0; l < LNUM; ++l) {
        rmsnorm_k<1><<<TOK, 64, 0, stream>>>(h, ln1 + l * HIDN, hn);
        qkv_k<<<dim3(3 * HH, BB), 64, 0, stream>>>(hn,
            WqT + l * WQKV, WkT + l * WQKV, WvT + l * WQKV,
            bq + l * HH * DD, bk + l * HH * DD, bv + l * HH * DD, qr, kr, vr);
        attn_part_k<<<dim3(BB * HH, NCH), 256, 0, stream>>>(qr, kr, vr,
            k_cache + (size_t)l * KVOFF, v_cache + (size_t)l * KVOFF, po, pml);
        attn_comb_k<<<BB * HH, 256, 0, stream>>>(po, pml, oa);
        gemm_res_k<HH * DD><<<dim3(12, 16), 64, 0, stream>>>(oa, WoT + l * WQKV, h);
        rmsnorm_k<1><<<TOK, 64, 0, stream>>>(h, ln2 + l * HIDN, hn);
        gemm_gu_k<<<dim3(32, 16), 64, 0, stream>>>(hn, WgT + l * WMLP, WuT + l * WMLP, fb);
        gemm_res_k<FFN><<<dim3(12, 16), 64, 0, stream>>>(fb, WdT + l * WMLP, h);
    }
    rmsnorm_k<0><<<TOK, 64, 0, stream>>>(h, normf, out);
}

// Round 4
// 504.760 us; speedup vs baseline: 3.2312x; 1.7562x over previous
//
#include <hip/hip_runtime.h>
#include <hip/hip_bf16.h>

#define LNUM 4
#define BB 16
#define SS 16
#define KVC 2048
#define HH 6
#define DD 128
#define HIDN 768
#define FFN 2048
#define NCH 17           // 16 cache chunks of 128 keys + 1 "new keys" chunk
#define ATT_SCALE 0.08838834764831845f
#define VT_PAD 136
#define OSH_PAD 132

typedef unsigned short u16;
typedef short s16x8 __attribute__((ext_vector_type(8)));
typedef unsigned short u16x4 __attribute__((ext_vector_type(4)));
typedef float f32x4 __attribute__((ext_vector_type(4)));

__device__ __forceinline__ short f2bfs(float f) {
    __hip_bfloat16 h = __float2bfloat16(f);   // RNE; pairs into v_cvt_pk_bf16_f32
    return *reinterpret_cast<short*>(&h);
}

// ---------- rope table: tab[s][d] = (sin, cos) for pos=KVC+s ---------------------------
__global__ __launch_bounds__(64) void rope_tab_k(float2* __restrict__ tab) {
    int i = blockIdx.x * 64 + threadIdx.x;   // 1024
    int s = i >> 6, d = i & 63;
    float ts = powf(10000.f, (float)d * (1.f / 64.f));
    float rad = (float)(KVC + s) / ts;
    tab[i] = make_float2(sinf(rad), cosf(rad));
}

// ---------- weight transpose+convert: in f32 [K][N] -> out bf16 [N][K], per layer z ----
// LDS row stride 65 u16: read-phase kg-step = 260 dw = 4 mod 32 -> conflict-free.
__global__ __launch_bounds__(256) void wtrans_k(const float* __restrict__ in,
                                                u16* __restrict__ out, int K, int N) {
    int n0 = blockIdx.x * 64, k0 = blockIdx.y * 64;
    size_t moff = (size_t)blockIdx.z * K * N;
    in += moff; out += moff;
    __shared__ u16 T[64][65];
    int t = threadIdx.x;
#pragma unroll
    for (int i = 0; i < 16; ++i) {
        int idx = i * 256 + t;
        int k = idx >> 6, n = idx & 63;
        T[k][n] = (u16)f2bfs(in[(size_t)(k0 + k) * N + n0 + n]);
    }
    __syncthreads();
#pragma unroll
    for (int i = 0; i < 2; ++i) {
        int idx = i * 256 + t;
        int n = idx >> 3, kg = idx & 7;
        s16x8 v;
#pragma unroll
        for (int j = 0; j < 8; ++j) v[j] = (short)T[kg * 8 + j][n];
        *(s16x8*)(out + (size_t)(n0 + n) * K + k0 + kg * 8) = v;
    }
}

// ---------- RMSNorm: one wave per token row; OUTBF: write bf16 else f32 ---------------
template<int OUTBF>
__global__ __launch_bounds__(64) void rmsnorm_k(const float* __restrict__ x,
                                                const float* __restrict__ w,
                                                void* __restrict__ yv) {
    int row = blockIdx.x, lane = threadIdx.x;
    const float* xp = x + (size_t)row * HIDN + lane * 12;
    float4 a = *(const float4*)xp;
    float4 b = *(const float4*)(xp + 4);
    float4 c = *(const float4*)(xp + 8);
    float s = a.x*a.x + a.y*a.y + a.z*a.z + a.w*a.w
            + b.x*b.x + b.y*b.y + b.z*b.z + b.w*b.w
            + c.x*c.x + c.y*c.y + c.z*c.z + c.w*c.w;
    for (int m = 1; m < 64; m <<= 1) s += __shfl_xor(s, m);
    float rq = rsqrtf(s * (1.f / 768.f) + 1e-6f);
    const float* wp = w + lane * 12;
    float v[12];
#pragma unroll
    for (int i = 0; i < 4; ++i) { v[i]   = (&a.x)[i] * rq * wp[i]; }
#pragma unroll
    for (int i = 0; i < 4; ++i) { v[4+i] = (&b.x)[i] * rq * wp[4+i]; }
#pragma unroll
    for (int i = 0; i < 4; ++i) { v[8+i] = (&c.x)[i] * rq * wp[8+i]; }
    if (OUTBF) {
        u16* y = (u16*)yv + (size_t)row * HIDN + lane * 12;
#pragma unroll
        for (int i = 0; i < 3; ++i) {
            u16x4 o;
#pragma unroll
            for (int j = 0; j < 4; ++j) o[j] = (u16)f2bfs(v[i * 4 + j]);
            *(u16x4*)(y + i * 4) = o;
        }
    } else {
        float* y = (float*)yv + (size_t)row * HIDN + lane * 12;
#pragma unroll
        for (int i = 0; i < 3; ++i) {
            float4 o; o.x = v[i*4]; o.y = v[i*4+1]; o.z = v[i*4+2]; o.w = v[i*4+3];
            *(float4*)(y + i * 4) = o;
        }
    }
}

// ---------- fused QKV GEMM + bias + rope(table) -> qr/kr/vr bf16 (b,h,s,d) ------------
__global__ __launch_bounds__(64) void qkv_k(const u16* __restrict__ hn,
                                            const u16* __restrict__ WqT, const u16* __restrict__ WkT,
                                            const u16* __restrict__ WvT,
                                            const float* __restrict__ bq, const float* __restrict__ bk,
                                            const float* __restrict__ bv,
                                            const float2* __restrict__ tab,
                                            u16* __restrict__ qr, u16* __restrict__ kr,
                                            u16* __restrict__ vr) {
    int x = blockIdx.x, b = blockIdx.y;
    int kind = x / HH, h = x % HH;
    const u16* Wt = (kind == 0) ? WqT : (kind == 1) ? WkT : WvT;
    const float* bias = (kind == 0) ? bq : (kind == 1) ? bk : bv;
    u16* outp = (kind == 0) ? qr : (kind == 1) ? kr : vr;
    int lane = threadIdx.x, r = lane & 15, qg = lane >> 4;
    f32x4 acc[8];
#pragma unroll
    for (int nt = 0; nt < 8; ++nt) acc[nt] = (f32x4){0.f, 0.f, 0.f, 0.f};
#pragma unroll 2
    for (int k0 = 0; k0 < HIDN; k0 += 32) {
        s16x8 a = *(const s16x8*)(hn + (size_t)(b * 16 + r) * HIDN + k0 + qg * 8);
#pragma unroll
        for (int nt = 0; nt < 8; ++nt) {
            s16x8 bw = *(const s16x8*)(Wt + (size_t)(h * DD + nt * 16 + r) * HIDN + k0 + qg * 8);
            acc[nt] = __builtin_amdgcn_mfma_f32_16x16x32_bf16(a, bw, acc[nt], 0, 0, 0);
        }
    }
    int bh = b * HH + h;
    if (kind < 2) {
#pragma unroll
        for (int nt = 0; nt < 4; ++nt) {
            int d1 = nt * 16 + r, d2 = d1 + 64;
            float b1 = bias[h * DD + d1], b2 = bias[h * DD + d2];
#pragma unroll
            for (int v = 0; v < 4; ++v) {
                int s = qg * 4 + v;
                float2 sc = tab[s * 64 + d1];
                float x1 = acc[nt][v] + b1;
                float x2 = acc[nt + 4][v] + b2;
                outp[(size_t)(bh * 16 + s) * DD + d1] = (u16)f2bfs(x1 * sc.y - x2 * sc.x);
                outp[(size_t)(bh * 16 + s) * DD + d2] = (u16)f2bfs(x2 * sc.y + x1 * sc.x);
            }
        }
    } else {
#pragma unroll
        for (int nt = 0; nt < 8; ++nt) {
            int d = nt * 16 + r;
            float bb = bias[h * DD + d];
#pragma unroll
            for (int v = 0; v < 4; ++v)
                outp[(size_t)(bh * 16 + qg * 4 + v) * DD + d] = (u16)f2bfs(acc[nt][v] + bb);
        }
    }
}

// ---------- attention partials: WG = 4 waves, 128 keys/WG, V staged transposed in LDS -
__global__ __launch_bounds__(256) void attn_part_k(
    const u16* __restrict__ qr, const u16* __restrict__ kr, const u16* __restrict__ vr,
    const float* __restrict__ kc, const float* __restrict__ vc,
    float* __restrict__ part_o, float* __restrict__ part_ml) {
    int bh = blockIdx.x, ch = blockIdx.y;
    int tid = threadIdx.x, wid = tid >> 6, lane = tid & 63, r = lane & 15, qg = lane >> 4;
    bool isnew = (ch == NCH - 1);
    bool active = !isnew || (wid == 0);
    __shared__ __align__(16) char smem[128 * VT_PAD * 2];  // Vt, later reused as Osh
    u16* Vt = (u16*)smem;
    float* Osh = (float*)smem;
    __shared__ __align__(16) u16 Plds[4][512];
    __shared__ float mlsh[4][32];

    const float* vbase_wg = vc + ((size_t)bh * KVC + ch * 128) * DD;
    const u16* vrn = vr + (size_t)bh * SS * DD;

    // ---- stage V -> Vt[d][key] (bf16, transposed)
    if (!isnew) {
#pragma unroll
        for (int i = 0; i < 8; ++i) {
            int flat = i * 256 + tid;
            int c4 = flat & 31, rp = flat >> 5;          // rp 0..63 -> rows 2rp, 2rp+1
            const float* p0 = vbase_wg + (size_t)(2 * rp) * DD + c4 * 4;
            float4 a = *(const float4*)p0;
            float4 b = *(const float4*)(p0 + DD);
#pragma unroll
            for (int c = 0; c < 4; ++c) {
                unsigned lo = (unsigned)(u16)f2bfs((&a.x)[c]);
                unsigned hi = (unsigned)(u16)f2bfs((&b.x)[c]);
                *(unsigned*)(Vt + (size_t)(c4 * 4 + c) * VT_PAD + 2 * rp) = lo | (hi << 16);
            }
        }
    } else {
#pragma unroll
        for (int i = 0; i < 16; ++i) {
            int flat = i * 256 + tid;                     // 32 keys x 128 d
            int key = flat >> 7, d = flat & 127;
            u16 v = (key < SS) ? vrn[(size_t)key * DD + d] : (u16)0;
            Vt[(size_t)d * VT_PAD + key] = v;
        }
    }
    __syncthreads();

    float mrow[4] = {-1e30f, -1e30f, -1e30f, -1e30f};
    float lrow[4] = {0.f, 0.f, 0.f, 0.f};
    f32x4 oacc[8];
#pragma unroll
    for (int nt = 0; nt < 8; ++nt) oacc[nt] = (f32x4){0.f, 0.f, 0.f, 0.f};

    if (active) {
        s16x8 aq[4];
#pragma unroll
        for (int kk = 0; kk < 4; ++kk)
            aq[kk] = *(const s16x8*)(qr + (size_t)(bh * 16 + r) * DD + kk * 32 + qg * 8);
        const float* kbase = kc + ((size_t)bh * KVC + ch * 128 + wid * 32) * DD;
        const u16* krn = kr + (size_t)bh * SS * DD;

        f32x4 st[2];
        st[0] = (f32x4){0.f,0.f,0.f,0.f};
        st[1] = (f32x4){0.f,0.f,0.f,0.f};
#pragma unroll
        for (int t = 0; t < 2; ++t) {
            if (isnew && t == 1) continue;
#pragma unroll
            for (int kk = 0; kk < 4; ++kk) {
                s16x8 bk;
                if (isnew) {
                    bk = *(const s16x8*)(krn + (size_t)(t * 16 + r) * DD + kk * 32 + qg * 8);
                } else {
                    const float* p = kbase + (size_t)(t * 16 + r) * DD + kk * 32 + qg * 8;
                    float4 xx = *(const float4*)p;
                    float4 yy = *(const float4*)(p + 4);
                    bk[0]=f2bfs(xx.x); bk[1]=f2bfs(xx.y); bk[2]=f2bfs(xx.z); bk[3]=f2bfs(xx.w);
                    bk[4]=f2bfs(yy.x); bk[5]=f2bfs(yy.y); bk[6]=f2bfs(yy.z); bk[7]=f2bfs(yy.w);
                }
                st[t] = __builtin_amdgcn_mfma_f32_16x16x32_bf16(aq[kk], bk, st[t], 0, 0, 0);
            }
        }
#pragma unroll
        for (int t = 0; t < 2; ++t)
#pragma unroll
            for (int v = 0; v < 4; ++v) st[t][v] *= ATT_SCALE;
        if (isnew) {
#pragma unroll
            for (int v = 0; v < 4; ++v) {
                if (r > qg * 4 + v) st[0][v] = -1e9f;
                st[1][v] = -1e9f;
            }
        }
#pragma unroll
        for (int v = 0; v < 4; ++v) {
            float xm = fmaxf(st[0][v], st[1][v]);
            for (int msk = 1; msk < 16; msk <<= 1) xm = fmaxf(xm, __shfl_xor(xm, msk));
            mrow[v] = xm;
        }
#pragma unroll
        for (int t = 0; t < 2; ++t)
#pragma unroll
            for (int v = 0; v < 4; ++v) st[t][v] = __expf(st[t][v] - mrow[v]);
#pragma unroll
        for (int v = 0; v < 4; ++v) {
            float ss = st[0][v] + st[1][v];
            for (int msk = 1; msk < 16; msk <<= 1) ss += __shfl_xor(ss, msk);
            lrow[v] = ss;
        }
        // P -> bf16 via per-wave LDS bounce (same-wave RAW, no barrier)
#pragma unroll
        for (int t = 0; t < 2; ++t)
#pragma unroll
            for (int v = 0; v < 4; ++v)
                Plds[wid][(qg * 4 + v) * 32 + t * 16 + r] = (u16)f2bfs(st[t][v]);
        s16x8 ap = *(const s16x8*)(&Plds[wid][r * 32 + qg * 8]);
#pragma unroll
        for (int nt = 0; nt < 8; ++nt) {
            s16x8 bv = *(const s16x8*)(Vt + (size_t)(nt * 16 + r) * VT_PAD + wid * 32 + qg * 8);
            oacc[nt] = __builtin_amdgcn_mfma_f32_16x16x32_bf16(ap, bv, oacc[nt], 0, 0, 0);
        }
    }
    __syncthreads();   // all Vt reads done; region becomes Osh
#pragma unroll
    for (int nt = 0; nt < 8; ++nt)
#pragma unroll
        for (int v = 0; v < 4; ++v)
            Osh[(size_t)(wid * 16 + qg * 4 + v) * OSH_PAD + nt * 16 + r] = oacc[nt][v];
    if (r == 0) {
#pragma unroll
        for (int v = 0; v < 4; ++v) {
            mlsh[wid][qg * 4 + v] = mrow[v];
            mlsh[wid][16 + qg * 4 + v] = lrow[v];
        }
    }
    __syncthreads();
    int q = tid >> 4, dg = tid & 15;
    float M = -1e30f;
#pragma unroll
    for (int w = 0; w < 4; ++w) M = fmaxf(M, mlsh[w][q]);
    float L = 0.f, wgt[4];
#pragma unroll
    for (int w = 0; w < 4; ++w) {
        wgt[w] = __expf(mlsh[w][q] - M);
        L += mlsh[w][16 + q] * wgt[w];
    }
    float o[8];
#pragma unroll
    for (int j = 0; j < 8; ++j) o[j] = 0.f;
#pragma unroll
    for (int w = 0; w < 4; ++w) {
        const float* op = Osh + (size_t)(w * 16 + q) * OSH_PAD + dg * 8;
        float4 a = *(const float4*)op;
        float4 b = *(const float4*)(op + 4);
        o[0]+=wgt[w]*a.x; o[1]+=wgt[w]*a.y; o[2]+=wgt[w]*a.z; o[3]+=wgt[w]*a.w;
        o[4]+=wgt[w]*b.x; o[5]+=wgt[w]*b.y; o[6]+=wgt[w]*b.z; o[7]+=wgt[w]*b.w;
    }
    float* po = part_o + ((size_t)bh * NCH + ch) * (SS * DD) + q * DD + dg * 8;
    float4 o0; o0.x=o[0]; o0.y=o[1]; o0.z=o[2]; o0.w=o[3];
    float4 o1; o1.x=o[4]; o1.y=o[5]; o1.z=o[6]; o1.w=o[7];
    *(float4*)po = o0;
    *(float4*)(po + 4) = o1;
    if (dg == 0) {
        float* pm = part_ml + ((size_t)bh * NCH + ch) * 32;
        pm[q] = M;
        pm[16 + q] = L;
    }
}

// ---------- combine partials -> oa bf16 (b,s,h*d) -------------------------------------
__global__ __launch_bounds__(256) void attn_comb_k(const float* __restrict__ part_o,
                                                   const float* __restrict__ part_ml,
                                                   u16* __restrict__ oa) {
    int bh = blockIdx.x, tid = threadIdx.x;
    __shared__ float sw[NCH][16], sLi[16];
    if (tid < 16) {
        float M = -1e30f;
        for (int c = 0; c < NCH; ++c) M = fmaxf(M, part_ml[((size_t)bh * NCH + c) * 32 + tid]);
        float L = 0.f;
        for (int c = 0; c < NCH; ++c) {
            const float* pm = part_ml + ((size_t)bh * NCH + c) * 32;
            float w = __expf(pm[tid] - M);
            sw[c][tid] = w;
            L += pm[16 + tid] * w;
        }
        sLi[tid] = 1.f / L;
    }
    __syncthreads();
    int q = tid >> 4, dg = tid & 15;
    float o[8];
#pragma unroll
    for (int j = 0; j < 8; ++j) o[j] = 0.f;
    for (int c = 0; c < NCH; ++c) {
        const float* po = part_o + ((size_t)bh * NCH + c) * (SS * DD) + q * DD + dg * 8;
        float4 a = *(const float4*)po;
        float4 b = *(const float4*)(po + 4);
        float w = sw[c][q];
        o[0]+=w*a.x; o[1]+=w*a.y; o[2]+=w*a.z; o[3]+=w*a.w;
        o[4]+=w*b.x; o[5]+=w*b.y; o[6]+=w*b.z; o[7]+=w*b.w;
    }
    float inv = sLi[q];
    int b = bh / HH, h = bh % HH;
    u16* yp = oa + (size_t)(b * SS + q) * HIDN + h * DD + dg * 8;
    s16x8 ov;
#pragma unroll
    for (int j = 0; j < 8; ++j) ov[j] = f2bfs(o[j] * inv);
    *(s16x8*)yp = ov;
}

// ---------- GEMM with residual: H[256][768] += A[256][K] @ Wt^T; optional split-K -----
template<int K, int KS>
__global__ __launch_bounds__(64) void gemm_res_k(const u16* __restrict__ A,
                                                 const u16* __restrict__ Wt,
                                                 float* __restrict__ H) {
    int lane = threadIdx.x, r = lane & 15, qg = lane >> 4;
    int n0 = blockIdx.x * 16, m0 = blockIdx.y * 16;
    const int KC = K / KS;
    int kbeg = blockIdx.z * KC;
    f32x4 acc = (f32x4){0.f, 0.f, 0.f, 0.f};
#pragma unroll 4
    for (int k0 = kbeg; k0 < kbeg + KC; k0 += 32) {
        s16x8 a  = *(const s16x8*)(A  + (size_t)(m0 + r) * K + k0 + qg * 8);
        s16x8 bw = *(const s16x8*)(Wt + (size_t)(n0 + r) * K + k0 + qg * 8);
        acc = __builtin_amdgcn_mfma_f32_16x16x32_bf16(a, bw, acc, 0, 0, 0);
    }
#pragma unroll
    for (int v = 0; v < 4; ++v) {
        size_t idx = (size_t)(m0 + qg * 4 + v) * HIDN + n0 + r;
        if (KS == 1) H[idx] += acc[v];
        else atomicAdd(&H[idx], acc[v]);
    }
}

// ---------- fused gate/up GEMM + SwiGLU -> fb bf16 [256][2048] -------------------------
__global__ __launch_bounds__(64) void gemm_gu_k(const u16* __restrict__ A,
                                                const u16* __restrict__ WgT,
                                                const u16* __restrict__ WuT,
                                                u16* __restrict__ F) {
    int lane = threadIdx.x, r = lane & 15, qg = lane >> 4;
    int n0 = blockIdx.x * 16, m0 = blockIdx.y * 16;
    f32x4 ag = (f32x4){0.f, 0.f, 0.f, 0.f};
    f32x4 au = (f32x4){0.f, 0.f, 0.f, 0.f};
#pragma unroll 2
    for (int k0 = 0; k0 < HIDN; k0 += 32) {
        s16x8 a  = *(const s16x8*)(A   + (size_t)(m0 + r) * HIDN + k0 + qg * 8);
        s16x8 bg = *(const s16x8*)(WgT + (size_t)(n0 + r) * HIDN + k0 + qg * 8);
        ag = __builtin_amdgcn_mfma_f32_16x16x32_bf16(a, bg, ag, 0, 0, 0);
        s16x8 bu = *(const s16x8*)(WuT + (size_t)(n0 + r) * HIDN + k0 + qg * 8);
        au = __builtin_amdgcn_mfma_f32_16x16x32_bf16(a, bu, au, 0, 0, 0);
    }
#pragma unroll
    for (int v = 0; v < 4; ++v) {
        float gv = ag[v], uv = au[v];
        float f = gv / (1.f + __expf(-gv)) * uv;
        F[(size_t)(m0 + qg * 4 + v) * FFN + n0 + r] = (u16)f2bfs(f);
    }
}

extern "C" void kernel_launch(void* const* d_in, const int* in_sizes, int n_in,
                              void* d_out, int out_size, void* d_ws, size_t ws_size,
                              hipStream_t stream) {
    (void)in_sizes; (void)n_in; (void)out_size; (void)ws_size;
    const float* emb     = (const float*)d_in[0];
    const float* k_cache = (const float*)d_in[4];
    const float* v_cache = (const float*)d_in[5];
    const float* Wq = (const float*)d_in[6];
    const float* bq = (const float*)d_in[7];
    const float* Wk = (const float*)d_in[8];
    const float* bk = (const float*)d_in[9];
    const float* Wv = (const float*)d_in[10];
    const float* bv = (const float*)d_in[11];
    const float* Wo = (const float*)d_in[12];
    const float* Wg = (const float*)d_in[13];
    const float* Wu = (const float*)d_in[14];
    const float* Wd = (const float*)d_in[15];
    const float* ln1 = (const float*)d_in[16];
    const float* ln2 = (const float*)d_in[17];
    const float* normf = (const float*)d_in[18];
    float* out = (float*)d_out;

    char* p = (char*)d_ws;
    auto alloc = [&](size_t bytes) { void* r = p; p += (bytes + 255) & ~255ull; return r; };
    const size_t WQKV = (size_t)HIDN * HH * DD;   // 589824
    const size_t WMLP = (size_t)HIDN * FFN;       // 1572864
    u16* WqT = (u16*)alloc(LNUM * WQKV * 2);
    u16* WkT = (u16*)alloc(LNUM * WQKV * 2);
    u16* WvT = (u16*)alloc(LNUM * WQKV * 2);
    u16* WoT = (u16*)alloc(LNUM * WQKV * 2);
    u16* WgT = (u16*)alloc(LNUM * WMLP * 2);
    u16* WuT = (u16*)alloc(LNUM * WMLP * 2);
    u16* WdT = (u16*)alloc(LNUM * WMLP * 2);
    const int TOK = BB * SS;
    const size_t EMB_N = (size_t)TOK * HIDN;
    float* h  = (float*)alloc(EMB_N * 4);
    u16* hn   = (u16*)alloc(EMB_N * 2);
    u16* qr   = (u16*)alloc((size_t)BB * HH * SS * DD * 2);
    u16* kr   = (u16*)alloc((size_t)BB * HH * SS * DD * 2);
    u16* vr   = (u16*)alloc((size_t)BB * HH * SS * DD * 2);
    u16* oa   = (u16*)alloc(EMB_N * 2);
    u16* fb   = (u16*)alloc((size_t)TOK * FFN * 2);
    float* po  = (float*)alloc((size_t)96 * NCH * SS * DD * 4);
    float* pml = (float*)alloc((size_t)96 * NCH * 32 * 4);
    float2* tab = (float2*)alloc(16 * 64 * sizeof(float2));

    rope_tab_k<<<16, 64, 0, stream>>>(tab);
    wtrans_k<<<dim3(12, 12, LNUM), 256, 0, stream>>>(Wq, WqT, HIDN, HH * DD);
    wtrans_k<<<dim3(12, 12, LNUM), 256, 0, stream>>>(Wk, WkT, HIDN, HH * DD);
    wtrans_k<<<dim3(12, 12, LNUM), 256, 0, stream>>>(Wv, WvT, HIDN, HH * DD);
    wtrans_k<<<dim3(12, 12, LNUM), 256, 0, stream>>>(Wo, WoT, HH * DD, HIDN);
    wtrans_k<<<dim3(32, 12, LNUM), 256, 0, stream>>>(Wg, WgT, HIDN, FFN);
    wtrans_k<<<dim3(32, 12, LNUM), 256, 0, stream>>>(Wu, WuT, HIDN, FFN);
    wtrans_k<<<dim3(12, 32, LNUM), 256, 0, stream>>>(Wd, WdT, FFN, HIDN);

    hipMemcpyAsync(h, emb, EMB_N * sizeof(float), hipMemcpyDeviceToDevice, stream);

    const size_t KVOFF = (size_t)BB * HH * KVC * DD;
    for (int l = 0; l < LNUM; ++l) {
        rmsnorm_k<1><<<TOK, 64, 0, stream>>>(h, ln1 + l * HIDN, hn);
        qkv_k<<<dim3(3 * HH, BB), 64, 0, stream>>>(hn,
            WqT + l * WQKV, WkT + l * WQKV, WvT + l * WQKV,
            bq + l * HH * DD, bk + l * HH * DD, bv + l * HH * DD, tab, qr, kr, vr);
        attn_part_k<<<dim3(BB * HH, NCH), 256, 0, stream>>>(qr, kr, vr,
            k_cache + (size_t)l * KVOFF, v_cache + (size_t)l * KVOFF, po, pml);
        attn_comb_k<<<BB * HH, 256, 0, stream>>>(po, pml, oa);
        gemm_res_k<HH * DD, 1><<<dim3(48, 16, 1), 64, 0, stream>>>(oa, WoT + l * WQKV, h);
        rmsnorm_k<1><<<TOK, 64, 0, stream>>>(h, ln2 + l * HIDN, hn);
        gemm_gu_k<<<dim3(128, 16), 64, 0, stream>>>(hn, WgT + l * WMLP, WuT + l * WMLP, fb);
        gemm_res_k<FFN, 4><<<dim3(48, 16, 4), 64, 0, stream>>>(fb, WdT + l * WMLP, h);
    }
    rmsnorm_k<0><<<TOK, 64, 0, stream>>>(h, normf, out);
}